// Round 4
// baseline (340.078 us; speedup 1.0000x reference)
//
#include <hip/hip_runtime.h>
#include <math.h>

#define NN 384
#define CC 128
#define MT (NN * NN)   // 147456 pairs

typedef __attribute__((ext_vector_type(8))) short bf16x8;   // 8 bf16 = 4 VGPRs (MFMA A/B frag)
typedef __attribute__((ext_vector_type(4))) short short4v;  // 8B packed bf16 store
typedef __attribute__((ext_vector_type(4))) float f32x4;    // MFMA acc frag

__device__ __forceinline__ float bf2f(short u) {
  union { float f; unsigned i; } v; v.i = ((unsigned)(unsigned short)u) << 16; return v.f;
}
__device__ __forceinline__ short f2bf(float f) {
  union { float f; unsigned i; } v; v.f = f;
  unsigned x = v.i;
  return (short)((x + 0x7fffu + ((x >> 16) & 1u)) >> 16);  // RNE
}
__device__ __forceinline__ void cp16(void* lds, const void* g) {
  __builtin_amdgcn_global_load_lds(
      (const __attribute__((address_space(1))) void*)g,
      (__attribute__((address_space(3))) void*)lds, 16, 0, 0);
}
__device__ __forceinline__ float sigm(float x) { return 1.f / (1.f + __expf(-x)); }

// LDS tile geometry (GEMM staging): [rows][64 bf16] = 128B rows = 8 x 16B slots.
// Swizzle: LDS[row][slot] holds global slot (slot ^ (row&7)).
//  - cp16 staging (linear LDS dest): lane l covers row (l>>3), slot (l&7) -> fetch
//    global slot (l&7)^(l>>3).
//  - read of global slot u for row r: LDS slot u ^ (r&7).

// ---------------------------------------------------------------- K0: weights fp32 -> bf16
// planes: [pa, ga, pb, gb, go, po']; po' = lw-scaled proj_o (LN fold)
__global__ __launch_bounds__(256) void k_wts(
    const float* __restrict__ w0, const float* __restrict__ w1,
    const float* __restrict__ w2, const float* __restrict__ w3,
    const float* __restrict__ w4, const float* __restrict__ w5,
    const float* __restrict__ lw, short* __restrict__ out)
{
  int idx = blockIdx.x * 256 + threadIdx.x;   // 0..98303
  const int plane = idx >> 14, q = idx & 16383;
  const float* s;
  switch (plane) {
    case 0: s = w0; break; case 1: s = w1; break; case 2: s = w2; break;
    case 3: s = w3; break; case 4: s = w4; break; default: s = w5; break;
  }
  float v = s[q];
  if (plane == 5) v *= lw[q & 127];
  out[idx] = f2bf(v);
}

// ---------------------------------------------------------------- K0b: S1[d]=sum lw*W, S2[d]=sum lb*W
__global__ void k_const(const float* __restrict__ po_w, const float* __restrict__ lw,
                        const float* __restrict__ lb, float* __restrict__ Sc)
{
  const int d = threadIdx.x;
  float s1 = 0.f, s2 = 0.f;
  for (int c = 0; c < 128; ++c) {
    const float w = po_w[d * 128 + c];
    s1 += lw[c] * w; s2 += lb[c] * w;
  }
  Sc[d] = s1; Sc[128 + d] = s2;
}

// ---------------------------------------------------------------- K1: LN(z) -> zn [p][c], zn_t [pT][c]
__global__ __launch_bounds__(256) void k_ln_in(
    const float* __restrict__ z, const float* __restrict__ lw,
    const float* __restrict__ lb, short* __restrict__ zn, short* __restrict__ zn_t)
{
  const int wid = threadIdx.x >> 6, lane = threadIdx.x & 63;
  const size_t p = (size_t)blockIdx.x * 4 + wid;   // one wave per row
  const int i = (int)(p / NN), j = (int)(p - (size_t)i * NN);
  const size_t pT = (size_t)j * NN + i;
  const float2 v = ((const float2*)(z + p * CC))[lane];
  float s = v.x + v.y, sq = v.x * v.x + v.y * v.y;
  #pragma unroll
  for (int o = 32; o > 0; o >>= 1) { s += __shfl_xor(s, o); sq += __shfl_xor(sq, o); }
  const float mu = s * (1.f / 128.f);
  const float rstd = rsqrtf(sq * (1.f / 128.f) - mu * mu + 1e-5f);
  const float2 w2 = ((const float2*)lw)[lane];
  const float2 b2 = ((const float2*)lb)[lane];
  short2 o2;
  o2.x = f2bf((v.x - mu) * rstd * w2.x + b2.x);
  o2.y = f2bf((v.y - mu) * rstd * w2.y + b2.y);
  ((short2*)(zn + p * CC))[lane] = o2;
  ((short2*)(zn_t + pT * CC))[lane] = o2;    // full 256B row, fire-and-forget
}

// ---------------------------------------------------------------- K2: paired linear
// wsa/wsb[c][y0*384+x0+m] = (proj+bp)*sigmoid(gate+bg)*mask[x,y]
// A rows come from zn_t: row r -> pair (k=x0+r, j=y0) -> zn_t[y0*384 + x0 + r]  (contiguous!)
__global__ __launch_bounds__(256) void k_lin(
    const short* __restrict__ znt, const short* __restrict__ Bw,
    const float* __restrict__ bias_p, const float* __restrict__ bias_g,
    const float* __restrict__ mask, short* __restrict__ outp)
{
  __shared__ char smem[49152];   // staging As 16K + Bs 32K | epilogue T[128][136]
  __shared__ float mask_s[128];
  short* As = (short*)smem;
  short* Bs = (short*)(smem + 16384);
  short* T  = (short*)smem;

  const int tid = threadIdx.x, wid = tid >> 6, lane = tid & 63;
  const int tile = blockIdx.x;
  const int y0 = tile / 3, x0 = (tile % 3) * 128;

  if (tid < 128) mask_s[tid] = mask[(size_t)(x0 + tid) * NN + y0];

  f32x4 accP[4][4], accG[4][4];
  #pragma unroll
  for (int i = 0; i < 4; ++i) {
    #pragma unroll
    for (int j = 0; j < 4; ++j) {
      accP[i][j] = f32x4{0.f, 0.f, 0.f, 0.f};
      accG[i][j] = f32x4{0.f, 0.f, 0.f, 0.f};
    }
  }
  const int wm = (wid >> 1) * 64, wn = (wid & 1) * 64;
  const int slot = (lane & 7) ^ (lane >> 3);   // swizzled global source slot

  #pragma unroll
  for (int kk = 0; kk < 2; ++kk) {          // K=128 in two 64-slices
    __syncthreads();
    #pragma unroll
    for (int i = 0; i < 4; ++i) {           // A tile: 128 rows x 64 k (contiguous rows)
      const int rbase = (i * 4 + wid) * 8;
      const int r = rbase + (lane >> 3);
      cp16((char*)As + rbase * 128,
           (const char*)(znt + ((size_t)y0 * NN + x0 + r) * CC) + kk * 128 + slot * 16);
    }
    #pragma unroll
    for (int i = 0; i < 8; ++i) {           // B tile: 256 rows (proj|gate) x 64 k
      const int rbase = (i * 4 + wid) * 8;
      const int r = rbase + (lane >> 3);
      cp16((char*)Bs + rbase * 128,
           (const char*)(Bw + (size_t)r * CC) + kk * 128 + slot * 16);
    }
    __syncthreads();
    #pragma unroll
    for (int ks = 0; ks < 2; ++ks) {
      const int u = ks * 4 + (lane >> 4);           // global 16B slot index
      const int sl = (u ^ (lane & 7)) * 8;          // swizzled LDS read (elements)
      bf16x8 a[4], bp[4], bg[4];
      #pragma unroll
      for (int f = 0; f < 4; ++f) {
        a[f]  = *(const bf16x8*)&As[(wm + f * 16 + (lane & 15)) * 64 + sl];
        bp[f] = *(const bf16x8*)&Bs[(wn + f * 16 + (lane & 15)) * 64 + sl];
        bg[f] = *(const bf16x8*)&Bs[128 * 64 + (wn + f * 16 + (lane & 15)) * 64 + sl];
      }
      #pragma unroll
      for (int fm = 0; fm < 4; ++fm) {
        #pragma unroll
        for (int fn = 0; fn < 4; ++fn) {
          accP[fm][fn] = __builtin_amdgcn_mfma_f32_16x16x32_bf16(a[fm], bp[fn], accP[fm][fn], 0, 0, 0);
          accG[fm][fn] = __builtin_amdgcn_mfma_f32_16x16x32_bf16(a[fm], bg[fn], accG[fm][fn], 0, 0, 0);
        }
      }
    }
  }

  // epilogue: transpose through LDS, then 256B-contiguous global rows
  __syncthreads();
  #pragma unroll
  for (int fm = 0; fm < 4; ++fm) {
    #pragma unroll
    for (int fn = 0; fn < 4; ++fn) {
      const int c = wn + fn * 16 + (lane & 15);
      const int mb = wm + fm * 16 + (lane >> 4) * 4;
      const float bpv = bias_p[c];
      const float bgv = bias_g[c];
      short4v st;
      #pragma unroll
      for (int e = 0; e < 4; ++e) {
        const float pv = accP[fm][fn][e] + bpv;
        const float gv = accG[fm][fn][e] + bgv;
        st[e] = f2bf(pv * sigm(gv) * mask_s[mb + e]);
      }
      *(short4v*)&T[c * 136 + mb] = st;          // T[c][x]
    }
  }
  __syncthreads();
  const size_t rowoff = (size_t)y0 * NN + x0;
  #pragma unroll
  for (int rep = 0; rep < 8; ++rep) {
    const int row = rep * 16 + (tid >> 4), chunk = tid & 15;
    const bf16x8 v = *(const bf16x8*)&T[row * 136 + chunk * 8];
    *(bf16x8*)(outp + (size_t)row * MT + rowoff + chunk * 8) = v;     // [c][..x]
  }
}

// ---------------------------------------------------------------- K3: per-channel triangle GEMM
// acc[m][n] = sum_k wsa[c][j0+m][k] * wsb[c][i0+n][k] = contracted[i0+n][j0+m][c]
__global__ __launch_bounds__(256) void k_tri(
    const short* __restrict__ wsa, const short* __restrict__ wsb,
    const float* __restrict__ mask, short* __restrict__ wsct)
{
  __shared__ char smem[34816];                // staging(32K) | T[128][136]
  short* As = (short*)smem;
  short* Bs = (short*)(smem + 16384);
  short* T  = (short*)smem;

  const int tid = threadIdx.x, wid = tid >> 6, lane = tid & 63;
  // XCD-chunked bijective remap: 144 consecutive orig blocks (16 channels) per XCD
  const int o = (blockIdx.x & 7) * 144 + (blockIdx.x >> 3);
  const int c = o / 9, t9 = o % 9;
  const int i0 = (t9 / 3) * 128, j0 = (t9 % 3) * 128;
  const short* Ab = wsa + (size_t)c * MT;   // rows j, 384 k
  const short* Bb = wsb + (size_t)c * MT;   // rows i, 384 k

  f32x4 acc[4][4];
  #pragma unroll
  for (int i = 0; i < 4; ++i) {
    #pragma unroll
    for (int j = 0; j < 4; ++j) acc[i][j] = f32x4{0.f, 0.f, 0.f, 0.f};
  }
  const int wm = (wid >> 1) * 64, wn = (wid & 1) * 64;
  const int slot = (lane & 7) ^ (lane >> 3);

  for (int kt = 0; kt < 6; ++kt) {          // K=384 in 64-slices
    __syncthreads();
    #pragma unroll
    for (int i = 0; i < 4; ++i) {
      const int rbase = (i * 4 + wid) * 8;
      const int r = rbase + (lane >> 3);
      cp16((char*)As + rbase * 128,
           (const char*)(Ab + (size_t)(j0 + r) * NN) + kt * 128 + slot * 16);
      cp16((char*)Bs + rbase * 128,
           (const char*)(Bb + (size_t)(i0 + r) * NN) + kt * 128 + slot * 16);
    }
    __syncthreads();
    #pragma unroll
    for (int ks = 0; ks < 2; ++ks) {
      const int u = ks * 4 + (lane >> 4);
      const int sl = (u ^ (lane & 7)) * 8;
      bf16x8 a[4], b[4];
      #pragma unroll
      for (int f = 0; f < 4; ++f) {
        a[f] = *(const bf16x8*)&As[(wm + f * 16 + (lane & 15)) * 64 + sl];
        b[f] = *(const bf16x8*)&Bs[(wn + f * 16 + (lane & 15)) * 64 + sl];
      }
      #pragma unroll
      for (int fm = 0; fm < 4; ++fm) {
        #pragma unroll
        for (int fn = 0; fn < 4; ++fn)
          acc[fm][fn] = __builtin_amdgcn_mfma_f32_16x16x32_bf16(a[fm], b[fn], acc[fm][fn], 0, 0, 0);
      }
    }
  }

  __syncthreads();
  #pragma unroll
  for (int fm = 0; fm < 4; ++fm) {
    #pragma unroll
    for (int fn = 0; fn < 4; ++fn) {
      const int il = wn + fn * 16 + (lane & 15);          // n -> i (local)
      const int jb = wm + fm * 16 + (lane >> 4) * 4;      // m -> j (4 consecutive)
      const f32x4 mk = *(const f32x4*)(mask + (size_t)(i0 + il) * NN + j0 + jb);
      short4v st;
      #pragma unroll
      for (int e = 0; e < 4; ++e) st[e] = f2bf(acc[fm][fn][e] * mk[e]);
      *(short4v*)&T[il * 136 + jb] = st;                  // T[i][j]
    }
  }
  __syncthreads();
  #pragma unroll
  for (int rep = 0; rep < 8; ++rep) {
    const int row = rep * 16 + (tid >> 4), chunk = tid & 15;
    const bf16x8 v = *(const bf16x8*)&T[row * 136 + chunk * 8];
    *(bf16x8*)(wsct + (size_t)c * MT + (size_t)(i0 + row) * NN + j0 + chunk * 8) = v;
  }
}

// ---------------------------------------------------------------- K4: fused LN-fold + proj_o + gate_o
// QK = A_raw @ W'^T ; out[p][d] = (rstd_p*(QK - mu_p*S1[d]) + S2[d] + po_b[d]) * sigm(gate+go_b)
__global__ __launch_bounds__(256) void k_fin(
    const short* __restrict__ wsct, const short* __restrict__ zn,
    const short* __restrict__ wpo /*lw-scaled bf16*/, const short* __restrict__ wgo,
    const float* __restrict__ Sc, const float* __restrict__ po_b,
    const float* __restrict__ go_b, float* __restrict__ out)
{
  // 0..32K: Tt[128c][128p] (phases A,C) / D-staging; 32K..64K: A1[2][128][64] swizzled;
  // 64K..: part[2][128] float2 (2K) + muS (512) + rsS (512)
  __shared__ char smem[68608];
  short*  Tt   = (short*)smem;
  short*  St   = (short*)smem;                  // D-phase staging alias
  short*  A1   = (short*)(smem + 32768);
  float2* part = (float2*)(smem + 65536);
  float*  muS  = (float*)(smem + 65536 + 2048);
  float*  rsS  = (float*)(smem + 65536 + 2048 + 512);

  const int tid = threadIdx.x, w = tid >> 6, lane = tid & 63;
  const size_t p0 = (size_t)blockIdx.x * 128;
  const int slot = (lane & 7) ^ (lane >> 3);

  // ---- phase A: stage Tt[c][p] linear (8 cp16/thread; 4 rows per wave-instr)
  #pragma unroll
  for (int i = 0; i < 8; ++i) {
    const int r0 = (i * 4 + w) * 4 + (lane >> 4);        // c row
    cp16((char*)Tt + (i * 4 + w) * 1024 + (lane & 48) * 16,
         (const char*)(wsct + (size_t)r0 * MT + p0) + (lane & 15) * 16);
  }
  __syncthreads();

  // ---- phase C: transpose Tt -> A1 (swizzled) + LN stats as by-product
  {
    const int pl = ((w & 1) << 6) | lane;     // 0..127, conflict-free row reads
    const int q  = w >> 1;                    // c-half = kk
    float s = 0.f, sq = 0.f;
    #pragma unroll
    for (int cb = 0; cb < 8; ++cb) {
      bf16x8 st;
      #pragma unroll
      for (int e = 0; e < 8; ++e) {
        const short u = Tt[(q * 64 + cb * 8 + e) * 128 + pl];
        const float f = bf2f(u);
        s += f; sq += f * f;
        st[e] = u;
      }
      *(bf16x8*)&A1[q * 8192 + pl * 64 + ((cb ^ (pl & 7)) << 3)] = st;
    }
    part[q * 128 + pl] = float2{s, sq};
  }
  __syncthreads();
  if (tid < 128) {
    const float2 a = part[tid], b = part[128 + tid];
    const float S = a.x + b.x, Q = a.y + b.y;
    const float mu = S * (1.f / 128.f);
    muS[tid] = mu;
    rsS[tid] = rsqrtf(Q * (1.f / 128.f) - mu * mu + 1e-5f);
  }

  const int wm = (w >> 1) * 64, wn = (w & 1) * 64;
  f32x4 accO[4][4], accG[4][4];
  #pragma unroll
  for (int i = 0; i < 4; ++i) {
    #pragma unroll
    for (int j = 0; j < 4; ++j) {
      accO[i][j] = f32x4{0.f, 0.f, 0.f, 0.f};
      accG[i][j] = f32x4{0.f, 0.f, 0.f, 0.f};
    }
  }

  // ---- phase D1: proj GEMM  (A = A1 from LDS, B = W' slice staged per kk)
  #pragma unroll
  for (int kk = 0; kk < 2; ++kk) {
    __syncthreads();                          // region0 free (C done / prev slice read)
    #pragma unroll
    for (int i = 0; i < 4; ++i) {             // W' slice: 128 rows x 64 k -> 16K
      const int rbase = (i * 4 + w) * 8;
      const int r = rbase + (lane >> 3);
      cp16((char*)St + rbase * 128, (const char*)(wpo + (size_t)r * CC) + kk * 128 + slot * 16);
    }
    __syncthreads();
    #pragma unroll
    for (int ks = 0; ks < 2; ++ks) {
      const int u = ks * 4 + (lane >> 4);
      const int sl = (u ^ (lane & 7)) * 8;
      bf16x8 a[4], b[4];
      #pragma unroll
      for (int f = 0; f < 4; ++f) {
        a[f] = *(const bf16x8*)&A1[kk * 8192 + (wm + f * 16 + (lane & 15)) * 64 + sl];
        b[f] = *(const bf16x8*)&St[(wn + f * 16 + (lane & 15)) * 64 + sl];
      }
      #pragma unroll
      for (int fm = 0; fm < 4; ++fm) {
        #pragma unroll
        for (int fn = 0; fn < 4; ++fn)
          accO[fm][fn] = __builtin_amdgcn_mfma_f32_16x16x32_bf16(a[fm], b[fn], accO[fm][fn], 0, 0, 0);
      }
    }
  }

  // ---- phase D2: gate GEMM  (A = zn slice, B = wgo slice, both staged per kk)
  #pragma unroll
  for (int kk = 0; kk < 2; ++kk) {
    __syncthreads();
    #pragma unroll
    for (int i = 0; i < 4; ++i) {
      const int rbase = (i * 4 + w) * 8;
      const int r = rbase + (lane >> 3);
      cp16((char*)St + rbase * 128,
           (const char*)(zn + (p0 + r) * CC) + kk * 128 + slot * 16);
      cp16((char*)St + 16384 + rbase * 128,
           (const char*)(wgo + (size_t)r * CC) + kk * 128 + slot * 16);
    }
    __syncthreads();
    #pragma unroll
    for (int ks = 0; ks < 2; ++ks) {
      const int u = ks * 4 + (lane >> 4);
      const int sl = (u ^ (lane & 7)) * 8;
      bf16x8 a[4], b[4];
      #pragma unroll
      for (int f = 0; f < 4; ++f) {
        a[f] = *(const bf16x8*)&St[(wm + f * 16 + (lane & 15)) * 64 + sl];
        b[f] = *(const bf16x8*)&St[8192 + (wn + f * 16 + (lane & 15)) * 64 + sl];
      }
      #pragma unroll
      for (int fm = 0; fm < 4; ++fm) {
        #pragma unroll
        for (int fn = 0; fn < 4; ++fn)
          accG[fm][fn] = __builtin_amdgcn_mfma_f32_16x16x32_bf16(a[fm], b[fn], accG[fm][fn], 0, 0, 0);
      }
    }
  }

  // ---- epilogue
  #pragma unroll
  for (int fm = 0; fm < 4; ++fm) {
    #pragma unroll
    for (int fn = 0; fn < 4; ++fn) {
      const int d = wn + fn * 16 + (lane & 15);
      const int mb = wm + fm * 16 + (lane >> 4) * 4;
      const float S1 = Sc[d], S2 = Sc[128 + d];
      const float bd = po_b[d], gd = go_b[d];
      #pragma unroll
      for (int e = 0; e < 4; ++e) {
        const int pl = mb + e;
        const float o = rsS[pl] * (accO[fm][fn][e] - muS[pl] * S1) + S2 + bd;
        const float g = sigm(accG[fm][fn][e] + gd);
        out[(p0 + pl) * CC + d] = o * g;
      }
    }
  }
}

// ----------------------------------------------------------------
extern "C" void kernel_launch(void* const* d_in, const int* in_sizes, int n_in,
                              void* d_out, int out_size, void* d_ws, size_t ws_size,
                              hipStream_t stream) {
  const float* z        = (const float*)d_in[0];
  const float* mask     = (const float*)d_in[1];
  const float* ln_in_w  = (const float*)d_in[2];
  const float* ln_in_b  = (const float*)d_in[3];
  const float* ln_out_w = (const float*)d_in[4];
  const float* ln_out_b = (const float*)d_in[5];
  const float* pa_w = (const float*)d_in[6];  const float* pa_b = (const float*)d_in[7];
  const float* ga_w = (const float*)d_in[8];  const float* ga_b = (const float*)d_in[9];
  const float* pb_w = (const float*)d_in[10]; const float* pb_b = (const float*)d_in[11];
  const float* gb_w = (const float*)d_in[12]; const float* gb_b = (const float*)d_in[13];
  const float* go_w = (const float*)d_in[14]; const float* go_b = (const float*)d_in[15];
  const float* po_w = (const float*)d_in[16]; const float* po_b = (const float*)d_in[17];

  char* ws = (char*)d_ws;
  const size_t SZ = (size_t)MT * CC * 2;     // 37.75 MB per bf16 plane (ws = 302 MB)
  short* zn   = (short*)(ws);                //  [p][c]
  short* zn_t = (short*)(ws + SZ);           //  [pT][c] transposed pair order
  short* wsa  = (short*)(ws + 2 * SZ);       //  [c][y][x]
  short* wsb  = (short*)(ws + 3 * SZ);       //  [c][y][x]
  short* wsct = (short*)(ws + 4 * SZ);       //  [c][i][j]
  short* wts  = (short*)(ws + 5 * SZ);       //  6x[128][128] bf16 (plane5 = lw-scaled po)
  float* Sc   = (float*)(ws + 5 * SZ + 6 * 16384 * 2);  // S1[128], S2[128]

  k_wts<<<384, 256, 0, stream>>>(pa_w, ga_w, pb_w, gb_w, go_w, po_w, ln_out_w, wts);
  k_const<<<1, 128, 0, stream>>>(po_w, ln_out_w, ln_out_b, Sc);
  k_ln_in<<<MT / 4, 256, 0, stream>>>(z, ln_in_w, ln_in_b, zn, zn_t);
  k_lin<<<1152, 256, 0, stream>>>(zn_t, wts,             pa_b, ga_b, mask, wsa);
  k_lin<<<1152, 256, 0, stream>>>(zn_t, wts + 2 * 16384, pb_b, gb_b, mask, wsb);
  k_tri<<<1152, 256, 0, stream>>>(wsa, wsb, mask, wsct);
  k_fin<<<1152, 256, 0, stream>>>(wsct, zn, wts + 5 * 16384, wts + 4 * 16384,
                                  Sc, po_b, go_b, (float*)d_out);
}